// Round 18
// baseline (165.912 us; speedup 1.0000x reference)
//
#include <hip/hip_runtime.h>

#define DEVI __device__ __forceinline__

typedef float f32x4 __attribute__((ext_vector_type(4)));
typedef float f32x16 __attribute__((ext_vector_type(16)));
typedef unsigned int u32x4 __attribute__((ext_vector_type(4)));
typedef unsigned int u32x2 __attribute__((ext_vector_type(2)));
typedef __bf16 bf16x8 __attribute__((ext_vector_type(8)));

#define NB 4
#define CIN 256
#define CI_ 128
#define NN 4096
// (1/sqrt(128)) * log2(e)  -- baked into Q projections; attn uses exp2
#define QSCALE 0.12752792233895158f

typedef unsigned short us;

DEVI us f2bf(float f) {
  unsigned int x = __float_as_uint(f);
  x += 0x7FFFu + ((x >> 16) & 1u);
  return (us)(x >> 16);
}

DEVI unsigned cvtpk(float lo, float hi) {
  unsigned r;
  asm("v_cvt_pk_bf16_f32 %0, %1, %2" : "=v"(r) : "v"(lo), "v"(hi));
  return r;
}

DEVI void plswap(unsigned& a, unsigned& b) {
  asm volatile("v_permlane32_swap_b32 %0, %1" : "+v"(a), "+v"(b));
}

DEVI float exp2fast(float x) {
#if __has_builtin(__builtin_amdgcn_exp2f)
  return __builtin_amdgcn_exp2f(x);
#else
  return exp2f(x);
#endif
}

DEVI f32x4 mfma16(u32x4 a, u32x4 b, f32x4 c) {
  return __builtin_amdgcn_mfma_f32_16x16x32_bf16(
      __builtin_bit_cast(bf16x8, a), __builtin_bit_cast(bf16x8, b), c, 0, 0, 0);
}

DEVI f32x16 mfma32(u32x4 a, u32x4 b, f32x16 c) {
  return __builtin_amdgcn_mfma_f32_32x32x16_bf16(
      __builtin_bit_cast(bf16x8, a), __builtin_bit_cast(bf16x8, b), c, 0, 0, 0);
}

DEVI void gload16(const void* g, void* l) {
  __builtin_amdgcn_global_load_lds(
      (const __attribute__((address_space(1))) void*)g,
      (__attribute__((address_space(3))) void*)l, 16, 0, 0);
}

// softmax-exp + pack P (D-layout, col q = l31) into PV A-frags. R8-verified.
DEVI void softpack(f32x16& a, float& ls, u32x4* pa) {
#pragma unroll
  for (int r = 0; r < 16; ++r) {
    float e = exp2fast(a[r]);
    ls += e;
    a[r] = e;
  }
  unsigned x0 = cvtpk(a[0], a[1]), z0 = cvtpk(a[2], a[3]);
  unsigned y0 = cvtpk(a[4], a[5]), t0 = cvtpk(a[6], a[7]);
  plswap(x0, y0);
  plswap(z0, t0);
  pa[0][0] = x0; pa[0][1] = z0; pa[0][2] = y0; pa[0][3] = t0;
  unsigned x1 = cvtpk(a[8], a[9]), z1 = cvtpk(a[10], a[11]);
  unsigned y1 = cvtpk(a[12], a[13]), t1 = cvtpk(a[14], a[15]);
  plswap(x1, y1);
  plswap(z1, t1);
  pa[1][0] = x1; pa[1][1] = z1; pa[1][2] = y1; pa[1][3] = t1;
}

// ---------------- Kernel 0: weight f32 -> bf16 pre-cast ----------------
__global__ __launch_bounds__(256) void wcvt_kernel(
    const float* __restrict__ hth_w, const float* __restrict__ hph_w,
    const float* __restrict__ th_w, const float* __restrict__ ph_w,
    const float* __restrict__ g_w, const float* __restrict__ Ww,
    us* __restrict__ wb) {
  const float* srcs[6] = {hth_w, hph_w, th_w, ph_w, g_w, Ww};
  const float* s = srcs[blockIdx.y];
  us* d = wb + blockIdx.y * 32768;
  int idx = (blockIdx.x * 256 + threadIdx.x) * 4;
  f32x4 v = *(const f32x4*)(s + idx);
  u32x2 o;
  o[0] = cvtpk(v[0], v[1]);
  o[1] = cvtpk(v[2], v[3]);
  *(u32x2*)(d + idx) = o;
}

// ---------------- Kernel A: 5 projection GEMMs (3-way split) ----------------
// grid (64, 4, 3): z=0 human -> hqT,hkT ; z=1 feats -> thT,phT ; z=2 feats -> gP
__global__ __launch_bounds__(256) void proj_kernel(
    const float* __restrict__ feats, const float* __restrict__ human,
    const float* __restrict__ g_b, const float* __restrict__ th_b,
    const float* __restrict__ ph_b, const float* __restrict__ hth_b,
    const float* __restrict__ hph_b, const us* __restrict__ wb,
    us* __restrict__ hqT, us* __restrict__ hkT,
    us* __restrict__ thT, us* __restrict__ phT, us* __restrict__ gP) {
  __shared__ alignas(16) us xt[64 * 256];  // [n][c] bf16, elem swz c^((n&15)<<3)
  const int t = threadIdx.x;
  const int b = blockIdx.y;
  const int n0 = blockIdx.x * 64;
  const int grp = blockIdx.z;
  const int w = t >> 6, l = t & 63, g16 = l >> 4, l15 = l & 15;
  const int tg = t >> 4, tl = t & 15;

  const float* src = (grp == 0) ? human : feats;
#pragma unroll
  for (int i = 0; i < 8; ++i) {
    int p = i * 16 + tg;  // c-pair 0..127
    const float* s0 = src + (size_t)(b * CIN + 2 * p) * NN + n0 + tl * 4;
    f32x4 v0 = *(const f32x4*)s0;
    f32x4 v1 = *(const f32x4*)(s0 + NN);
#pragma unroll
    for (int j = 0; j < 4; ++j) {
      int row = tl * 4 + j;
      *(unsigned*)((char*)xt + row * 512 + ((4 * p) ^ ((row & 15) << 4))) =
          cvtpk(v0[j], v1[j]);
    }
  }
  __syncthreads();

  if (grp < 2) {
    const float* pb2[2] = {grp ? th_b : hth_b, grp ? ph_b : hph_b};
    us* pout2[2] = {grp ? thT : hqT, grp ? phT : hkT};
    const us* wb0 = wb + grp * 2 * 32768;

    // Transposed projections: M = n (rows), N = ci, K = c
    u32x4 afrag[8];
    const int arow = w * 16 + l15;
#pragma unroll
    for (int s = 0; s < 8; ++s)
      afrag[s] = *(const u32x4*)((const char*)xt + arow * 512 +
                                 (((s << 6) | (g16 << 4)) ^ (l15 << 4)));
    for (int p = 0; p < 2; ++p) {
      const us* wbp = wb0 + p * 32768;
      const float scl = (p == 0) ? QSCALE : 1.0f;
      for (int nt = 0; nt < 8; ++nt) {
        f32x4 acc = {0.f, 0.f, 0.f, 0.f};
#pragma unroll
        for (int s = 0; s < 8; ++s) {
          u32x4 bf = *(const u32x4*)(wbp + (nt * 16 + l15) * 256 + s * 32 + g16 * 8);
          acc = mfma16(afrag[s], bf, acc);
        }
        float bias = pb2[p][nt * 16 + l15];
#pragma unroll
        for (int r = 0; r < 4; ++r) {
          int nrow = n0 + w * 16 + g16 * 4 + r;
          pout2[p][((size_t)b * NN + nrow) * CI_ + nt * 16 + l15] =
              f2bf((acc[r] + bias) * scl);
        }
      }
    }
  } else {
    // g projection: M = ci, N = n, K = c  (B-frags from xt tile)
    const us* wbg = wb + 4 * 32768;
    u32x4 ag[2][8];
#pragma unroll
    for (int mt = 0; mt < 2; ++mt)
#pragma unroll
      for (int s = 0; s < 8; ++s)
        ag[mt][s] = *(const u32x4*)(wbg + (w * 32 + mt * 16 + l15) * 256 + s * 32 + g16 * 8);
    float gb[2][4];
#pragma unroll
    for (int mt = 0; mt < 2; ++mt)
#pragma unroll
      for (int r = 0; r < 4; ++r) gb[mt][r] = g_b[w * 32 + mt * 16 + g16 * 4 + r];
    for (int nt = 0; nt < 4; ++nt) {
      f32x4 acc0 = {0.f, 0.f, 0.f, 0.f}, acc1 = {0.f, 0.f, 0.f, 0.f};
#pragma unroll
      for (int s = 0; s < 8; ++s) {
        u32x4 bf = *(const u32x4*)((const char*)xt + (nt * 16 + l15) * 512 +
                                   ((s * 64 + g16 * 16) ^ (l15 << 4)));
        acc0 = mfma16(ag[0][s], bf, acc0);
        acc1 = mfma16(ag[1][s], bf, acc1);
      }
#pragma unroll
      for (int r = 0; r < 4; ++r) {
        int ci0 = w * 32 + g16 * 4 + r;
        gP[((size_t)b * CI_ + ci0) * NN + n0 + nt * 16 + l15] = f2bf(acc0[r] + gb[0][r]);
        gP[((size_t)b * CI_ + ci0 + 16) * NN + n0 + nt * 16 + l15] = f2bf(acc1[r] + gb[1][r]);
      }
    }
  }
}

// ---------------- Kernel B: dual-path flash attention, T4 counted-vmcnt ----
// grid 1024 = 8 (xcd: b,path) x 2 (K-half) x 64 (q-chunk 64); 128 thr = 2 waves.
// KVBLK=32, TRIPLE-buffered (48 KB). Per iter: vmcnt(8) (stage(kt) done,
// stage(kt+1) in flight across barrier) -> raw s_barrier -> issue stage(kt+2)
// -> compute(kt). Otherwise identical to the R8-verified kernel.
__global__ __launch_bounds__(128, 2) void attn_kernel(
    const us* __restrict__ hqT, const us* __restrict__ hkT,
    const us* __restrict__ thT, const us* __restrict__ phT,
    const us* __restrict__ gP, us* __restrict__ PY, float* __restrict__ PL) {
  // sB[buf][0] = K tile ([key][d] 256B rows, unit swz u^(key&15))
  // sB[buf][1] = V tile (quad-rows: R=d>>2, 256B, swz u^(R&15))
  __shared__ alignas(16) us sB[3][2][32 * 128];

  const int t = threadIdx.x, w = t >> 6, l = t & 63;
  const int l31 = l & 31, hi = l >> 5, l15 = l & 15;
  const int id = blockIdx.x;
  const int bp = id & 7, b = bp & 3, path = bp >> 2;
  const int r2 = id >> 3, h = r2 & 1, chunk = r2 >> 1;
  const int qw = chunk * 64 + w * 32, kb = h * 2048;
  const us* Qs = (path ? thT : hqT) + (size_t)b * NN * CI_;
  const char* Kb = (const char*)((path ? phT : hkT) + (size_t)b * NN * CI_);
  const char* Vb = (const char*)(gP + (size_t)b * CI_ * NN);

  // Q B-frags: col q = l31, k = s*16 + hi*8 + j
  u32x4 aQ[8];
#pragma unroll
  for (int s = 0; s < 8; ++s)
    aQ[s] = *(const u32x4*)(Qs + (size_t)(qw + l31) * CI_ + s * 16 + hi * 8);

  f32x16 Y[4];
#pragma unroll
  for (int ds = 0; ds < 4; ++ds) Y[ds] = 0.f;
  float lsum = 0.f;

  const int sr = l >> 4;  // staging sub-row

  auto stage = [&](int k0, int buf) {
#pragma unroll
    for (int i = 0; i < 4; ++i) {
      int row = w * 16 + i * 4 + sr;
      gload16(Kb + (size_t)(k0 + row) * 256 + (((l & 15) ^ (row & 15)) << 4),
              (char*)sB[buf][0] + (w * 16 + i * 4) * 256);
    }
#pragma unroll
    for (int i = 0; i < 4; ++i) {
      int R = w * 16 + i * 4 + sr;
      int lu = (l & 15) ^ (R & 15);
      int d = 4 * R + (lu >> 2);
      gload16(Vb + (size_t)d * 8192 + (size_t)k0 * 2 + (lu & 3) * 16,
              (char*)sB[buf][1] + (w * 16 + i * 4) * 256);
    }
  };

  // prologue: two tiles in flight
  stage(kb, 0);
  stage(kb + 32, 1);

  for (int kt = 0; kt < 64; ++kt) {
    // stage(kt) must be complete; stage(kt+1)'s 8 loads may stay in flight.
    if (kt < 63)
      asm volatile("s_waitcnt vmcnt(8)" ::: "memory");
    else
      asm volatile("s_waitcnt vmcnt(0)" ::: "memory");
    __builtin_amdgcn_s_barrier();
    __builtin_amdgcn_sched_barrier(0);
    if (kt < 62) stage(kb + (kt + 2) * 32, (kt + 2) % 3);

    const char* kt_ = (const char*)sB[kt % 3][0];
    const char* vt_ = (const char*)sB[kt % 3][1];

    // ---- QK^T (swapped): A = K rows (key=l31), B = Q -> D[key][q=l31 col]
    f32x16 a0 = 0.f;
    __builtin_amdgcn_s_setprio(1);
#pragma unroll
    for (int s = 0; s < 8; ++s) {
      u32x4 ak = *(const u32x4*)(kt_ + l31 * 256 + (((s * 2 + hi) ^ l15) << 4));
      a0 = mfma32(ak, aQ[s], a0);
    }
    __builtin_amdgcn_s_setprio(0);

    u32x4 pa[2];
    softpack(a0, lsum, pa);

    // ---- PV: A = P (row q = l31 of D-layout), B = V (col d = l31)
    __builtin_amdgcn_s_setprio(1);
#pragma unroll
    for (int ds = 0; ds < 4; ++ds) {
      int R = ds * 8 + (l31 >> 2);
      const char* vb = vt_ + R * 256;
      int k_ = R & 15;
      u32x4 v0 = *(const u32x4*)(vb + ((((l31 & 3) * 4 + hi) ^ k_) << 4));
      u32x4 v1 = *(const u32x4*)(vb + ((((l31 & 3) * 4 + 2 + hi) ^ k_) << 4));
      Y[ds] = mfma32(pa[0], v0, Y[ds]);
      Y[ds] = mfma32(pa[1], v1, Y[ds]);
    }
    __builtin_amdgcn_s_setprio(0);
  }
  __syncthreads();  // all waves done with compute(63) before buffer reuse

  // ---------------- per-wave epilogue ----------------
  lsum += __shfl_xor(lsum, 32);
  if (hi == 0) PL[(size_t)(h * 8 + bp) * NN + qw + l31] = lsum;

  // wave-private 16 KB transpose buffer: [128 d][32 q] f32, swz u^(d&7)
  float* buf = (float*)((char*)sB + w * 16384);
#pragma unroll
  for (int ds = 0; ds < 4; ++ds) {
    int d = ds * 32 + l31;
#pragma unroll
    for (int m = 0; m < 4; ++m) {
      f32x4 v = {Y[ds][4 * m], Y[ds][4 * m + 1], Y[ds][4 * m + 2],
                 Y[ds][4 * m + 3]};
      *(f32x4*)((char*)buf + d * 128 + (((2 * m + hi) ^ (d & 7)) << 4)) = v;
    }
  }
  float yv[64];
#pragma unroll
  for (int j = 0; j < 64; ++j) {
    int d = hi * 64 + j;
    yv[j] = *(const float*)((char*)buf + d * 128 +
                            ((((l31 >> 2) ^ (d & 7)) << 4)) + (l31 & 3) * 4);
  }
  us* dst = PY + ((size_t)(h * 8 + bp) * NN + qw + l31) * CI_ + hi * 64;
#pragma unroll
  for (int o = 0; o < 8; ++o) {
    u32x4 pk;
#pragma unroll
    for (int e = 0; e < 4; ++e)
      pk[e] = cvtpk(yv[o * 8 + 2 * e], yv[o * 8 + 2 * e + 1]);
    *(u32x4*)(dst + o * 8) = pk;
  }
}

// ---------------- Kernel C: combine halves + W conv + BN (R14-exact) -------
// grid (64, 4): combine ONCE per 64-row n-tile, then loop all 4 o-tiles.
__global__ __launch_bounds__(256) void wout_kernel(
    const us* __restrict__ PY, const float* __restrict__ PL,
    const us* __restrict__ wb, const float* __restrict__ Wb,
    const float* __restrict__ gamma, const float* __restrict__ beta,
    const float* __restrict__ mean, const float* __restrict__ var,
    float* __restrict__ out) {
  __shared__ alignas(16) us sY[64 * 128];  // [n][ci], byte swz ((n&7)<<4)
  const int t = threadIdx.x, w = t >> 6, l = t & 63, g16 = l >> 4, l15 = l & 15;
  const int n0 = blockIdx.x * 64;
  const int b = blockIdx.y;

  {
    const int row = t >> 2, cg = t & 3;
    const int n = n0 + row;
    float acc[32];
#pragma unroll
    for (int e = 0; e < 32; ++e) acc[e] = 0.f;
#pragma unroll
    for (int p = 0; p < 2; ++p) {
      int bpi = p * 4 + b;
      float sc = 0.5f / (PL[(size_t)bpi * NN + n] + PL[(size_t)(8 + bpi) * NN + n]);
#pragma unroll
      for (int hh = 0; hh < 2; ++hh) {
        const us* src = PY + (size_t)(hh * 8 + bpi) * (NN * CI_) +
                        (size_t)n * CI_ + cg * 32;
#pragma unroll
        for (int j = 0; j < 4; ++j) {
          u32x4 v = *(const u32x4*)(src + j * 8);
#pragma unroll
          for (int e = 0; e < 4; ++e) {
            unsigned u = v[e];
            acc[j * 8 + 2 * e] += __uint_as_float(u << 16) * sc;
            acc[j * 8 + 2 * e + 1] += __uint_as_float(u & 0xFFFF0000u) * sc;
          }
        }
      }
    }
#pragma unroll
    for (int j = 0; j < 4; ++j) {
      u32x4 o;
#pragma unroll
      for (int e = 0; e < 4; ++e)
        o[e] = cvtpk(acc[j * 8 + 2 * e], acc[j * 8 + 2 * e + 1]);
      *(u32x4*)((char*)sY + row * 256 + ((cg * 64 + j * 16) ^ ((row & 7) << 4))) = o;
    }
  }
  __syncthreads();

  const us* wbw = wb + 5 * 32768;
  for (int ob4 = 0; ob4 < 4; ++ob4) {
    const int ob = ob4 * 64;
    u32x4 aW[4];
    const int orow = ob + w * 16 + l15;
#pragma unroll
    for (int s = 0; s < 4; ++s)
      aW[s] = *(const u32x4*)(wbw + orow * 128 + s * 32 + g16 * 8);
    float wbias[4], inv_[4], mu[4], bt[4];
#pragma unroll
    for (int r = 0; r < 4; ++r) {
      int o = ob + w * 16 + g16 * 4 + r;
      wbias[r] = Wb[o];
      inv_[r] = gamma[o] * rsqrtf(var[o] + 1e-5f);
      mu[r] = mean[o];
      bt[r] = beta[o];
    }

    for (int nt = 0; nt < 4; ++nt) {
      f32x4 acc = {0.f, 0.f, 0.f, 0.f};
#pragma unroll
      for (int s = 0; s < 4; ++s) {
        u32x4 bf = *(const u32x4*)((const char*)sY + (nt * 16 + l15) * 256 +
                                   (((s << 6) | (g16 << 4)) ^ ((l15 & 7) << 4)));
        acc = mfma16(aW[s], bf, acc);
      }
#pragma unroll
      for (int r = 0; r < 4; ++r) {
        int o = ob + w * 16 + g16 * 4 + r;
        out[((size_t)b * CIN + o) * NN + n0 + nt * 16 + l15] =
            (acc[r] + wbias[r] - mu[r]) * inv_[r] + bt[r];
      }
    }
  }
}

extern "C" void kernel_launch(void* const* d_in, const int* in_sizes, int n_in,
                              void* d_out, int out_size, void* d_ws, size_t ws_size,
                              hipStream_t stream) {
  const float* feats = (const float*)d_in[0];
  const float* human = (const float*)d_in[1];
  const float* g_w = (const float*)d_in[2];
  const float* g_b = (const float*)d_in[3];
  const float* th_w = (const float*)d_in[4];
  const float* th_b = (const float*)d_in[5];
  const float* ph_w = (const float*)d_in[6];
  const float* ph_b = (const float*)d_in[7];
  const float* hth_w = (const float*)d_in[8];
  const float* hth_b = (const float*)d_in[9];
  const float* hph_w = (const float*)d_in[10];
  const float* hph_b = (const float*)d_in[11];
  const float* Ww = (const float*)d_in[12];
  const float* Wb = (const float*)d_in[13];
  const float* gamma = (const float*)d_in[14];
  const float* beta = (const float*)d_in[15];
  const float* mean = (const float*)d_in[16];
  const float* var = (const float*)d_in[17];

  us* ws = (us*)d_ws;
  const size_t SZ = (size_t)NB * NN * CI_;  // 2,097,152 us per projection
  us* hqT = ws;
  us* hkT = ws + SZ;
  us* thT = ws + 2 * SZ;
  us* phT = ws + 3 * SZ;
  us* gP = ws + 4 * SZ;
  us* PY = ws + 5 * SZ;                          // [2h][8bp][4096][128] = 8,388,608 us
  float* PL = (float*)(ws + 5 * SZ + 8388608);   // 2*8*4096 f32 = 131,072 us
  us* wb = ws + 5 * SZ + 8388608 + 131072;       // 6*32768 us

  wcvt_kernel<<<dim3(32, 6), 256, 0, stream>>>(hth_w, hph_w, th_w, ph_w, g_w, Ww, wb);
  proj_kernel<<<dim3(64, 4, 3), 256, 0, stream>>>(feats, human, g_b, th_b, ph_b,
                                                  hth_b, hph_b, wb, hqT, hkT,
                                                  thT, phT, gP);
  attn_kernel<<<1024, 128, 0, stream>>>(hqT, hkT, thT, phT, gP, PY, PL);
  wout_kernel<<<dim3(64, 4), 256, 0, stream>>>(PY, PL, wb, Wb, gamma, beta,
                                               mean, var, (float*)d_out);
}

// Round 19
// 135.890 us; speedup vs baseline: 1.2209x; 1.2209x over previous
//
#include <hip/hip_runtime.h>

#define DEVI __device__ __forceinline__

typedef float f32x4 __attribute__((ext_vector_type(4)));
typedef float f32x16 __attribute__((ext_vector_type(16)));
typedef unsigned int u32x4 __attribute__((ext_vector_type(4)));
typedef unsigned int u32x2 __attribute__((ext_vector_type(2)));
typedef __bf16 bf16x8 __attribute__((ext_vector_type(8)));

#define NB 4
#define CIN 256
#define CI_ 128
#define NN 4096
// (1/sqrt(128)) * log2(e)  -- baked into Q projections; attn uses exp2
#define QSCALE 0.12752792233895158f

typedef unsigned short us;

DEVI us f2bf(float f) {
  unsigned int x = __float_as_uint(f);
  x += 0x7FFFu + ((x >> 16) & 1u);
  return (us)(x >> 16);
}

DEVI unsigned cvtpk(float lo, float hi) {
  unsigned r;
  asm("v_cvt_pk_bf16_f32 %0, %1, %2" : "=v"(r) : "v"(lo), "v"(hi));
  return r;
}

DEVI void plswap(unsigned& a, unsigned& b) {
  asm volatile("v_permlane32_swap_b32 %0, %1" : "+v"(a), "+v"(b));
}

DEVI float exp2fast(float x) {
#if __has_builtin(__builtin_amdgcn_exp2f)
  return __builtin_amdgcn_exp2f(x);
#else
  return exp2f(x);
#endif
}

DEVI f32x4 mfma16(u32x4 a, u32x4 b, f32x4 c) {
  return __builtin_amdgcn_mfma_f32_16x16x32_bf16(
      __builtin_bit_cast(bf16x8, a), __builtin_bit_cast(bf16x8, b), c, 0, 0, 0);
}

DEVI f32x16 mfma32(u32x4 a, u32x4 b, f32x16 c) {
  return __builtin_amdgcn_mfma_f32_32x32x16_bf16(
      __builtin_bit_cast(bf16x8, a), __builtin_bit_cast(bf16x8, b), c, 0, 0, 0);
}

DEVI void gload16(const void* g, void* l) {
  __builtin_amdgcn_global_load_lds(
      (const __attribute__((address_space(1))) void*)g,
      (__attribute__((address_space(3))) void*)l, 16, 0, 0);
}

// softmax-exp + pack P (D-layout, col q = l31) into PV A-frags. R8-verified.
DEVI void softpack(f32x16& a, float& ls, u32x4* pa) {
#pragma unroll
  for (int r = 0; r < 16; ++r) {
    float e = exp2fast(a[r]);
    ls += e;
    a[r] = e;
  }
  unsigned x0 = cvtpk(a[0], a[1]), z0 = cvtpk(a[2], a[3]);
  unsigned y0 = cvtpk(a[4], a[5]), t0 = cvtpk(a[6], a[7]);
  plswap(x0, y0);
  plswap(z0, t0);
  pa[0][0] = x0; pa[0][1] = z0; pa[0][2] = y0; pa[0][3] = t0;
  unsigned x1 = cvtpk(a[8], a[9]), z1 = cvtpk(a[10], a[11]);
  unsigned y1 = cvtpk(a[12], a[13]), t1 = cvtpk(a[14], a[15]);
  plswap(x1, y1);
  plswap(z1, t1);
  pa[1][0] = x1; pa[1][1] = z1; pa[1][2] = y1; pa[1][3] = t1;
}

// ---------------- Kernel 0: weight f32 -> bf16 pre-cast ----------------
__global__ __launch_bounds__(256) void wcvt_kernel(
    const float* __restrict__ hth_w, const float* __restrict__ hph_w,
    const float* __restrict__ th_w, const float* __restrict__ ph_w,
    const float* __restrict__ g_w, const float* __restrict__ Ww,
    us* __restrict__ wb) {
  const float* srcs[6] = {hth_w, hph_w, th_w, ph_w, g_w, Ww};
  const float* s = srcs[blockIdx.y];
  us* d = wb + blockIdx.y * 32768;
  int idx = (blockIdx.x * 256 + threadIdx.x) * 4;
  f32x4 v = *(const f32x4*)(s + idx);
  u32x2 o;
  o[0] = cvtpk(v[0], v[1]);
  o[1] = cvtpk(v[2], v[3]);
  *(u32x2*)(d + idx) = o;
}

// ---------------- Kernel A: 5 projection GEMMs (3-way split) ----------------
// grid (64, 4, 3): z=0 human -> hqT,hkT ; z=1 feats -> thT,phT ; z=2 feats -> gP
__global__ __launch_bounds__(256) void proj_kernel(
    const float* __restrict__ feats, const float* __restrict__ human,
    const float* __restrict__ g_b, const float* __restrict__ th_b,
    const float* __restrict__ ph_b, const float* __restrict__ hth_b,
    const float* __restrict__ hph_b, const us* __restrict__ wb,
    us* __restrict__ hqT, us* __restrict__ hkT,
    us* __restrict__ thT, us* __restrict__ phT, us* __restrict__ gP) {
  __shared__ alignas(16) us xt[64 * 256];  // [n][c] bf16, elem swz c^((n&15)<<3)
  const int t = threadIdx.x;
  const int b = blockIdx.y;
  const int n0 = blockIdx.x * 64;
  const int grp = blockIdx.z;
  const int w = t >> 6, l = t & 63, g16 = l >> 4, l15 = l & 15;
  const int tg = t >> 4, tl = t & 15;

  const float* src = (grp == 0) ? human : feats;
#pragma unroll
  for (int i = 0; i < 8; ++i) {
    int p = i * 16 + tg;  // c-pair 0..127
    const float* s0 = src + (size_t)(b * CIN + 2 * p) * NN + n0 + tl * 4;
    f32x4 v0 = *(const f32x4*)s0;
    f32x4 v1 = *(const f32x4*)(s0 + NN);
#pragma unroll
    for (int j = 0; j < 4; ++j) {
      int row = tl * 4 + j;
      *(unsigned*)((char*)xt + row * 512 + ((4 * p) ^ ((row & 15) << 4))) =
          cvtpk(v0[j], v1[j]);
    }
  }
  __syncthreads();

  if (grp < 2) {
    const float* pb2[2] = {grp ? th_b : hth_b, grp ? ph_b : hph_b};
    us* pout2[2] = {grp ? thT : hqT, grp ? phT : hkT};
    const us* wb0 = wb + grp * 2 * 32768;

    // Transposed projections: M = n (rows), N = ci, K = c
    u32x4 afrag[8];
    const int arow = w * 16 + l15;
#pragma unroll
    for (int s = 0; s < 8; ++s)
      afrag[s] = *(const u32x4*)((const char*)xt + arow * 512 +
                                 (((s << 6) | (g16 << 4)) ^ (l15 << 4)));
    for (int p = 0; p < 2; ++p) {
      const us* wbp = wb0 + p * 32768;
      const float scl = (p == 0) ? QSCALE : 1.0f;
      for (int nt = 0; nt < 8; ++nt) {
        f32x4 acc = {0.f, 0.f, 0.f, 0.f};
#pragma unroll
        for (int s = 0; s < 8; ++s) {
          u32x4 bf = *(const u32x4*)(wbp + (nt * 16 + l15) * 256 + s * 32 + g16 * 8);
          acc = mfma16(afrag[s], bf, acc);
        }
        float bias = pb2[p][nt * 16 + l15];
#pragma unroll
        for (int r = 0; r < 4; ++r) {
          int nrow = n0 + w * 16 + g16 * 4 + r;
          pout2[p][((size_t)b * NN + nrow) * CI_ + nt * 16 + l15] =
              f2bf((acc[r] + bias) * scl);
        }
      }
    }
  } else {
    // g projection: M = ci, N = n, K = c  (B-frags from xt tile)
    const us* wbg = wb + 4 * 32768;
    u32x4 ag[2][8];
#pragma unroll
    for (int mt = 0; mt < 2; ++mt)
#pragma unroll
      for (int s = 0; s < 8; ++s)
        ag[mt][s] = *(const u32x4*)(wbg + (w * 32 + mt * 16 + l15) * 256 + s * 32 + g16 * 8);
    float gb[2][4];
#pragma unroll
    for (int mt = 0; mt < 2; ++mt)
#pragma unroll
      for (int r = 0; r < 4; ++r) gb[mt][r] = g_b[w * 32 + mt * 16 + g16 * 4 + r];
    for (int nt = 0; nt < 4; ++nt) {
      f32x4 acc0 = {0.f, 0.f, 0.f, 0.f}, acc1 = {0.f, 0.f, 0.f, 0.f};
#pragma unroll
      for (int s = 0; s < 8; ++s) {
        u32x4 bf = *(const u32x4*)((const char*)xt + (nt * 16 + l15) * 512 +
                                   ((s * 64 + g16 * 16) ^ (l15 << 4)));
        acc0 = mfma16(ag[0][s], bf, acc0);
        acc1 = mfma16(ag[1][s], bf, acc1);
      }
#pragma unroll
      for (int r = 0; r < 4; ++r) {
        int ci0 = w * 32 + g16 * 4 + r;
        gP[((size_t)b * CI_ + ci0) * NN + n0 + nt * 16 + l15] = f2bf(acc0[r] + gb[0][r]);
        gP[((size_t)b * CI_ + ci0 + 16) * NN + n0 + nt * 16 + l15] = f2bf(acc1[r] + gb[1][r]);
      }
    }
  }
}

// ---------------- Kernel B: dual-path flash attention (R8-exact) ----------
// grid 1024 = 8 (xcd: b,path) x 2 (K-half) x 64 (q-chunk 64); 128 thr = 2 waves.
// KVBLK=32, double-buffered. Each wave: ONE 32-q subtile, full 32-key tile,
// 32x32 MFMA, in-register P. Partial Y (bf16) + PL; wout combines.
__global__ __launch_bounds__(128, 2) void attn_kernel(
    const us* __restrict__ hqT, const us* __restrict__ hkT,
    const us* __restrict__ thT, const us* __restrict__ phT,
    const us* __restrict__ gP, us* __restrict__ PY, float* __restrict__ PL) {
  __shared__ alignas(16) us sK[2][32 * 128];  // [key][d] 256B rows, unit swz u^(key&15)
  __shared__ alignas(16) us sV[2][32 * 128];  // quad-rows: R=d>>2, 256B, swz u^(R&15)

  const int t = threadIdx.x, w = t >> 6, l = t & 63;
  const int l31 = l & 31, hi = l >> 5, l15 = l & 15;
  const int id = blockIdx.x;
  const int bp = id & 7, b = bp & 3, path = bp >> 2;
  const int r2 = id >> 3, h = r2 & 1, chunk = r2 >> 1;
  const int qw = chunk * 64 + w * 32, kb = h * 2048;
  const us* Qs = (path ? thT : hqT) + (size_t)b * NN * CI_;
  const char* Kb = (const char*)((path ? phT : hkT) + (size_t)b * NN * CI_);
  const char* Vb = (const char*)(gP + (size_t)b * CI_ * NN);

  // Q B-frags: col q = l31, k = s*16 + hi*8 + j
  u32x4 aQ[8];
#pragma unroll
  for (int s = 0; s < 8; ++s)
    aQ[s] = *(const u32x4*)(Qs + (size_t)(qw + l31) * CI_ + s * 16 + hi * 8);

  f32x16 Y[4];
#pragma unroll
  for (int ds = 0; ds < 4; ++ds) Y[ds] = 0.f;
  float lsum = 0.f;

  const int sr = l >> 4;  // staging sub-row

  auto stage = [&](int k0, int buf) {
#pragma unroll
    for (int i = 0; i < 4; ++i) {
      int row = w * 16 + i * 4 + sr;
      gload16(Kb + (size_t)(k0 + row) * 256 + (((l & 15) ^ (row & 15)) << 4),
              (char*)sK[buf] + (w * 16 + i * 4) * 256);
    }
#pragma unroll
    for (int i = 0; i < 4; ++i) {
      int R = w * 16 + i * 4 + sr;
      int lu = (l & 15) ^ (R & 15);
      int d = 4 * R + (lu >> 2);
      gload16(Vb + (size_t)d * 8192 + (size_t)k0 * 2 + (lu & 3) * 16,
              (char*)sV[buf] + (w * 16 + i * 4) * 256);
    }
  };

  stage(kb, 0);
  __syncthreads();

  for (int kt = 0; kt < 64; ++kt) {
    const int cur = kt & 1;
    if (kt < 63) stage(kb + (kt + 1) * 32, cur ^ 1);
    const char* kt_ = (const char*)sK[cur];
    const char* vt_ = (const char*)sV[cur];

    // ---- QK^T (swapped): A = K rows (key=l31), B = Q -> D[key][q=l31 col]
    f32x16 a0 = 0.f;
    __builtin_amdgcn_s_setprio(1);
#pragma unroll
    for (int s = 0; s < 8; ++s) {
      u32x4 ak = *(const u32x4*)(kt_ + l31 * 256 + (((s * 2 + hi) ^ l15) << 4));
      a0 = mfma32(ak, aQ[s], a0);
    }
    __builtin_amdgcn_s_setprio(0);

    u32x4 pa[2];
    softpack(a0, lsum, pa);

    // ---- PV: A = P (row q = l31 of D-layout), B = V (col d = l31)
    __builtin_amdgcn_s_setprio(1);
#pragma unroll
    for (int ds = 0; ds < 4; ++ds) {
      int R = ds * 8 + (l31 >> 2);
      const char* vb = vt_ + R * 256;
      int k_ = R & 15;
      u32x4 v0 = *(const u32x4*)(vb + ((((l31 & 3) * 4 + hi) ^ k_) << 4));
      u32x4 v1 = *(const u32x4*)(vb + ((((l31 & 3) * 4 + 2 + hi) ^ k_) << 4));
      Y[ds] = mfma32(pa[0], v0, Y[ds]);
      Y[ds] = mfma32(pa[1], v1, Y[ds]);
    }
    __builtin_amdgcn_s_setprio(0);
    __syncthreads();
  }

  // ---------------- per-wave epilogue ----------------
  lsum += __shfl_xor(lsum, 32);
  if (hi == 0) PL[(size_t)(h * 8 + bp) * NN + qw + l31] = lsum;

  // wave-private 16 KB transpose buffer: [128 d][32 q] f32, swz u^(d&7)
  float* buf = (float*)(w ? (us*)sV : (us*)sK);
#pragma unroll
  for (int ds = 0; ds < 4; ++ds) {
    int d = ds * 32 + l31;
#pragma unroll
    for (int m = 0; m < 4; ++m) {
      f32x4 v = {Y[ds][4 * m], Y[ds][4 * m + 1], Y[ds][4 * m + 2],
                 Y[ds][4 * m + 3]};
      *(f32x4*)((char*)buf + d * 128 + (((2 * m + hi) ^ (d & 7)) << 4)) = v;
    }
  }
  float yv[64];
#pragma unroll
  for (int j = 0; j < 64; ++j) {
    int d = hi * 64 + j;
    yv[j] = *(const float*)((char*)buf + d * 128 +
                            ((((l31 >> 2) ^ (d & 7)) << 4)) + (l31 & 3) * 4);
  }
  us* dst = PY + ((size_t)(h * 8 + bp) * NN + qw + l31) * CI_ + hi * 64;
#pragma unroll
  for (int o = 0; o < 8; ++o) {
    u32x4 pk;
#pragma unroll
    for (int e = 0; e < 4; ++e)
      pk[e] = cvtpk(yv[o * 8 + 2 * e], yv[o * 8 + 2 * e + 1]);
    *(u32x4*)(dst + o * 8) = pk;
  }
}

// ---------------- Kernel C: combine halves + W conv + BN (R14-exact) -------
// grid (64, 4): combine ONCE per 64-row n-tile, then loop all 4 o-tiles.
__global__ __launch_bounds__(256) void wout_kernel(
    const us* __restrict__ PY, const float* __restrict__ PL,
    const us* __restrict__ wb, const float* __restrict__ Wb,
    const float* __restrict__ gamma, const float* __restrict__ beta,
    const float* __restrict__ mean, const float* __restrict__ var,
    float* __restrict__ out) {
  __shared__ alignas(16) us sY[64 * 128];  // [n][ci], byte swz ((n&7)<<4)
  const int t = threadIdx.x, w = t >> 6, l = t & 63, g16 = l >> 4, l15 = l & 15;
  const int n0 = blockIdx.x * 64;
  const int b = blockIdx.y;

  {
    const int row = t >> 2, cg = t & 3;
    const int n = n0 + row;
    float acc[32];
#pragma unroll
    for (int e = 0; e < 32; ++e) acc[e] = 0.f;
#pragma unroll
    for (int p = 0; p < 2; ++p) {
      int bpi = p * 4 + b;
      float sc = 0.5f / (PL[(size_t)bpi * NN + n] + PL[(size_t)(8 + bpi) * NN + n]);
#pragma unroll
      for (int hh = 0; hh < 2; ++hh) {
        const us* src = PY + (size_t)(hh * 8 + bpi) * (NN * CI_) +
                        (size_t)n * CI_ + cg * 32;
#pragma unroll
        for (int j = 0; j < 4; ++j) {
          u32x4 v = *(const u32x4*)(src + j * 8);
#pragma unroll
          for (int e = 0; e < 4; ++e) {
            unsigned u = v[e];
            acc[j * 8 + 2 * e] += __uint_as_float(u << 16) * sc;
            acc[j * 8 + 2 * e + 1] += __uint_as_float(u & 0xFFFF0000u) * sc;
          }
        }
      }
    }
#pragma unroll
    for (int j = 0; j < 4; ++j) {
      u32x4 o;
#pragma unroll
      for (int e = 0; e < 4; ++e)
        o[e] = cvtpk(acc[j * 8 + 2 * e], acc[j * 8 + 2 * e + 1]);
      *(u32x4*)((char*)sY + row * 256 + ((cg * 64 + j * 16) ^ ((row & 7) << 4))) = o;
    }
  }
  __syncthreads();

  const us* wbw = wb + 5 * 32768;
  for (int ob4 = 0; ob4 < 4; ++ob4) {
    const int ob = ob4 * 64;
    u32x4 aW[4];
    const int orow = ob + w * 16 + l15;
#pragma unroll
    for (int s = 0; s < 4; ++s)
      aW[s] = *(const u32x4*)(wbw + orow * 128 + s * 32 + g16 * 8);
    float wbias[4], inv_[4], mu[4], bt[4];
#pragma unroll
    for (int r = 0; r < 4; ++r) {
      int o = ob + w * 16 + g16 * 4 + r;
      wbias[r] = Wb[o];
      inv_[r] = gamma[o] * rsqrtf(var[o] + 1e-5f);
      mu[r] = mean[o];
      bt[r] = beta[o];
    }

    for (int nt = 0; nt < 4; ++nt) {
      f32x4 acc = {0.f, 0.f, 0.f, 0.f};
#pragma unroll
      for (int s = 0; s < 4; ++s) {
        u32x4 bf = *(const u32x4*)((const char*)sY + (nt * 16 + l15) * 256 +
                                   (((s << 6) | (g16 << 4)) ^ ((l15 & 7) << 4)));
        acc = mfma16(aW[s], bf, acc);
      }
#pragma unroll
      for (int r = 0; r < 4; ++r) {
        int o = ob + w * 16 + g16 * 4 + r;
        out[((size_t)b * CIN + o) * NN + n0 + nt * 16 + l15] =
            (acc[r] + wbias[r] - mu[r]) * inv_[r] + bt[r];
      }
    }
  }
}

extern "C" void kernel_launch(void* const* d_in, const int* in_sizes, int n_in,
                              void* d_out, int out_size, void* d_ws, size_t ws_size,
                              hipStream_t stream) {
  const float* feats = (const float*)d_in[0];
  const float* human = (const float*)d_in[1];
  const float* g_w = (const float*)d_in[2];
  const float* g_b = (const float*)d_in[3];
  const float* th_w = (const float*)d_in[4];
  const float* th_b = (const float*)d_in[5];
  const float* ph_w = (const float*)d_in[6];
  const float* ph_b = (const float*)d_in[7];
  const float* hth_w = (const float*)d_in[8];
  const float* hth_b = (const float*)d_in[9];
  const float* hph_w = (const float*)d_in[10];
  const float* hph_b = (const float*)d_in[11];
  const float* Ww = (const float*)d_in[12];
  const float* Wb = (const float*)d_in[13];
  const float* gamma = (const float*)d_in[14];
  const float* beta = (const float*)d_in[15];
  const float* mean = (const float*)d_in[16];
  const float* var = (const float*)d_in[17];

  us* ws = (us*)d_ws;
  const size_t SZ = (size_t)NB * NN * CI_;  // 2,097,152 us per projection
  us* hqT = ws;
  us* hkT = ws + SZ;
  us* thT = ws + 2 * SZ;
  us* phT = ws + 3 * SZ;
  us* gP = ws + 4 * SZ;
  us* PY = ws + 5 * SZ;                          // [2h][8bp][4096][128] = 8,388,608 us
  float* PL = (float*)(ws + 5 * SZ + 8388608);   // 2*8*4096 f32 = 131,072 us
  us* wb = ws + 5 * SZ + 8388608 + 131072;       // 6*32768 us

  wcvt_kernel<<<dim3(32, 6), 256, 0, stream>>>(hth_w, hph_w, th_w, ph_w, g_w, Ww, wb);
  proj_kernel<<<dim3(64, 4, 3), 256, 0, stream>>>(feats, human, g_b, th_b, ph_b,
                                                  hth_b, hph_b, wb, hqT, hkT,
                                                  thT, phT, gP);
  attn_kernel<<<1024, 128, 0, stream>>>(hqT, hkT, thT, phT, gP, PY, PL);
  wout_kernel<<<dim3(64, 4), 256, 0, stream>>>(PY, PL, wb, Wb, gamma, beta,
                                               mean, var, (float*)d_out);
}